// Round 2
// baseline (2590.429 us; speedup 1.0000x reference)
//
#include <hip/hip_runtime.h>
#include <hip/hip_bf16.h>
#include <stdint.h>

// Problem constants
#define TT   8192      // tokens = B*S
#define DD   2048      // d_model
#define FF   5632      // ffn hidden
#define EE   8         // experts
#define RR   16        // lora rank
#define NALL 11520     // F + F + E*2R = 5632+5632+256
#define NPAIR 16384    // T * TOPK

typedef float  f32x4  __attribute__((ext_vector_type(4)));
typedef __bf16 bf16x8 __attribute__((ext_vector_type(8)));
typedef __bf16 bf16x4 __attribute__((ext_vector_type(4)));

#define AS1CAST(p) ((__attribute__((address_space(1))) void*)(p))
#define AS3CAST(p) ((__attribute__((address_space(3))) void*)(p))

// ---------------------------------------------------------------------------
// f32 -> bf16 convert (float4 vectorized, grid-stride)
// ---------------------------------------------------------------------------
__global__ __launch_bounds__(256) void cvt_f32_bf16(const float* __restrict__ src,
                                                    __bf16* __restrict__ dst, int n4) {
    int stride = gridDim.x * 256;
    for (int i = blockIdx.x * 256 + threadIdx.x; i < n4; i += stride) {
        float4 v = ((const float4*)src)[i];
        bf16x4 o = {(__bf16)v.x, (__bf16)v.y, (__bf16)v.z, (__bf16)v.w};
        ((bf16x4*)dst)[i] = o;
    }
}

// Gather-convert A1/A3 into stacked rows [256][D]: row j=e*32+l, l<16 -> A1[e][l], else A3[e][l-16]
__global__ __launch_bounds__(256) void cvt_A13(const float* __restrict__ A1,
                                               const float* __restrict__ A3,
                                               __bf16* __restrict__ dst) {
    int i = blockIdx.x * 256 + threadIdx.x;   // [0, 256*512)
    int col4 = i & 511;                       // D/4 = 512
    int j = i >> 9;                           // row 0..255
    int e = j >> 5, l = j & 31;
    const float* src = (l < 16) ? (A1 + (size_t)(e * 16 + l) * DD)
                                : (A3 + (size_t)(e * 16 + (l - 16)) * DD);
    float4 v = ((const float4*)src)[col4];
    bf16x4 o = {(__bf16)v.x, (__bf16)v.y, (__bf16)v.z, (__bf16)v.w};
    ((bf16x4*)(dst + (size_t)j * DD))[col4] = o;
}

// ---------------------------------------------------------------------------
// Router: logits (fp32, output #2), top-2 renormalized weights per token
// 4 tokens per block, one wave per token
// ---------------------------------------------------------------------------
__global__ __launch_bounds__(256) void router_k(const float* __restrict__ x,
                                                const float* __restrict__ gw,
                                                float* __restrict__ logits,
                                                int* __restrict__ pair_e,
                                                float* __restrict__ pair_w) {
    int t = blockIdx.x * 4 + (threadIdx.x >> 6);
    int lane = threadIdx.x & 63;
    const float* xr = x + (size_t)t * DD;
    float acc[EE];
#pragma unroll
    for (int e = 0; e < EE; e++) acc[e] = 0.f;
    for (int d = lane; d < DD; d += 64) {
        float xv = xr[d];
#pragma unroll
        for (int e = 0; e < EE; e++) acc[e] += xv * gw[e * DD + d];
    }
#pragma unroll
    for (int off = 32; off > 0; off >>= 1) {
#pragma unroll
        for (int e = 0; e < EE; e++) acc[e] += __shfl_down(acc[e], off, 64);
    }
    if (lane == 0) {
        float mx = acc[0];
#pragma unroll
        for (int e = 1; e < EE; e++) mx = fmaxf(mx, acc[e]);
        float p[EE];
#pragma unroll
        for (int e = 0; e < EE; e++) p[e] = __expf(acc[e] - mx);
        int e0 = 0;
#pragma unroll
        for (int e = 1; e < EE; e++) if (p[e] > p[e0]) e0 = e;
        int e1 = (e0 == 0) ? 1 : 0;
#pragma unroll
        for (int e = 0; e < EE; e++) if (e != e0 && p[e] > p[e1]) e1 = e;
        float s = p[e0] + p[e1];
        pair_e[2 * t] = e0;     pair_e[2 * t + 1] = e1;
        pair_w[2 * t] = p[e0] / s; pair_w[2 * t + 1] = p[e1] / s;
#pragma unroll
        for (int e = 0; e < EE; e++) logits[(size_t)t * EE + e] = acc[e];
    }
}

// ---------------------------------------------------------------------------
// m97-style bf16 GEMM, B^T layout: C[M,N] = A[M,K] * B[N,K]^T
// 128x128 block tile, 4 waves (2x2), 4x4 16x16x32 MFMA per wave, BK=32
// global_load_lds width-16 staging, fp32 or bf16 output
// ---------------------------------------------------------------------------
template <int OUT_BF16>
__global__ __launch_bounds__(256) void gemm_bt(const __bf16* __restrict__ A,
                                               const __bf16* __restrict__ B,
                                               void* __restrict__ Cv,
                                               int M, int N, int K) {
    __shared__ __align__(16) __bf16 As[128 * 32];
    __shared__ __align__(16) __bf16 Bs[128 * 32];
    const int tid  = threadIdx.x;
    const int wave = tid >> 6, lane = tid & 63;
    const int quad = lane >> 4, lrow = lane & 15;
    const int m0 = blockIdx.x * 128, n0 = blockIdx.y * 128;

    // staging addresses: flat byte = j*4096 + tid*16; row = flat/64, colb = flat%64
    const int r0  = (tid << 4) >> 6;          // rows 0..63
    const int cb0 = (tid << 4) & 63;
    const size_t ldb = (size_t)K * 2;
    const char* gA0 = (const char*)A + (size_t)(m0 + r0) * ldb + cb0;
    const char* gA1 = (const char*)A + (size_t)(m0 + r0 + 64) * ldb + cb0;
    const char* gB0 = (const char*)B + (size_t)(n0 + r0) * ldb + cb0;
    const char* gB1 = (const char*)B + (size_t)(n0 + r0 + 64) * ldb + cb0;
    char* lA0 = ((char*)As) + (wave << 10);
    char* lA1 = ((char*)As) + 4096 + (wave << 10);
    char* lB0 = ((char*)Bs) + (wave << 10);
    char* lB1 = ((char*)Bs) + 4096 + (wave << 10);

    f32x4 acc[4][4] = {};

    const int abase = ((wave & 1) * 64 + lrow) * 32 + quad * 8;
    const int bbase = ((wave >> 1) * 64 + lrow) * 32 + quad * 8;

    const int KB = K * 2;   // bytes per row
    for (int kb = 0; kb < KB; kb += 64) {
        __syncthreads();
        __builtin_amdgcn_global_load_lds(AS1CAST((void*)(gA0 + kb)), AS3CAST(lA0), 16, 0, 0);
        __builtin_amdgcn_global_load_lds(AS1CAST((void*)(gA1 + kb)), AS3CAST(lA1), 16, 0, 0);
        __builtin_amdgcn_global_load_lds(AS1CAST((void*)(gB0 + kb)), AS3CAST(lB0), 16, 0, 0);
        __builtin_amdgcn_global_load_lds(AS1CAST((void*)(gB1 + kb)), AS3CAST(lB1), 16, 0, 0);
        __syncthreads();

        bf16x8 af[4], bfr[4];
#pragma unroll
        for (int i = 0; i < 4; i++) af[i]  = *(const bf16x8*)&As[abase + i * 16 * 32];
#pragma unroll
        for (int j = 0; j < 4; j++) bfr[j] = *(const bf16x8*)&Bs[bbase + j * 16 * 32];
#pragma unroll
        for (int i = 0; i < 4; i++)
#pragma unroll
            for (int j = 0; j < 4; j++)
                acc[i][j] = __builtin_amdgcn_mfma_f32_16x16x32_bf16(af[i], bfr[j], acc[i][j], 0, 0, 0);
    }

    const int wm = (wave & 1) * 64, wn = (wave >> 1) * 64;
#pragma unroll
    for (int i = 0; i < 4; i++) {
#pragma unroll
        for (int j = 0; j < 4; j++) {
#pragma unroll
            for (int r = 0; r < 4; r++) {
                int row = m0 + wm + i * 16 + quad * 4 + r;
                int col = n0 + wn + j * 16 + lrow;
                float v = acc[i][j][r];
                if (OUT_BF16) ((__bf16*)Cv)[(size_t)row * N + col] = (__bf16)v;
                else          ((float*)Cv)[(size_t)row * N + col] = v;
            }
        }
    }
}

// ---------------------------------------------------------------------------
// Per-pair: u1 = base1 + ha1*B1[e]^T, u3 = base3 + ha3*B3[e]^T,
// g = silu(u1)*u3 -> G (bf16); also GA[p,r] = sum_f g*A2[e][r,f]
// base row layout: [0:F)=base1, [F:2F)=base3, [2F + e*32 + {0..15,16..31}] = ha1,ha3
// Chunked: blockIdx.x = local pair lp; global pair p = p0 + lp; base row = lp>>1.
// ---------------------------------------------------------------------------
__global__ __launch_bounds__(256) void g_build(const __bf16* __restrict__ base,
                                               const float* __restrict__ B1,
                                               const float* __restrict__ B3,
                                               const float* __restrict__ A2,
                                               const int* __restrict__ pair_e,
                                               __bf16* __restrict__ G,
                                               float* __restrict__ GA,
                                               int p0) {
    const int lp = blockIdx.x;
    const int p = p0 + lp;
    const int lt = lp >> 1;
    const int tid = threadIdx.x;
    const int e = pair_e[p];
    __shared__ float ha1[RR], ha3[RR];
    __shared__ float red[4][RR];
    const __bf16* brow = base + (size_t)lt * NALL;
    if (tid < 32) {
        float v = (float)brow[2 * FF + e * 32 + tid];
        if (tid < 16) ha1[tid] = v; else ha3[tid - 16] = v;
    }
    __syncthreads();
    const float* B1e = B1 + (size_t)e * FF * RR;
    const float* B3e = B3 + (size_t)e * FF * RR;
    const float* A2e = A2 + (size_t)e * RR * FF;
    float ga[RR];
#pragma unroll
    for (int r = 0; r < RR; r++) ga[r] = 0.f;
    for (int f = tid; f < FF; f += 256) {
        float u1 = (float)brow[f];
        float u3 = (float)brow[FF + f];
        const float4* b1 = (const float4*)(B1e + (size_t)f * RR);
        const float4* b3 = (const float4*)(B3e + (size_t)f * RR);
#pragma unroll
        for (int q = 0; q < 4; q++) {
            float4 v1 = b1[q], v3 = b3[q];
            u1 += ha1[q * 4 + 0] * v1.x + ha1[q * 4 + 1] * v1.y + ha1[q * 4 + 2] * v1.z + ha1[q * 4 + 3] * v1.w;
            u3 += ha3[q * 4 + 0] * v3.x + ha3[q * 4 + 1] * v3.y + ha3[q * 4 + 2] * v3.z + ha3[q * 4 + 3] * v3.w;
        }
        float g = (u1 / (1.f + __expf(-u1))) * u3;   // silu(u1)*u3
        G[(size_t)lp * FF + f] = (__bf16)g;
#pragma unroll
        for (int r = 0; r < RR; r++) ga[r] += g * A2e[(size_t)r * FF + f];
    }
    const int lane = tid & 63, wave = tid >> 6;
#pragma unroll
    for (int off = 32; off > 0; off >>= 1) {
#pragma unroll
        for (int r = 0; r < RR; r++) ga[r] += __shfl_down(ga[r], off, 64);
    }
    if (lane == 0) {
#pragma unroll
        for (int r = 0; r < RR; r++) red[wave][r] = ga[r];
    }
    __syncthreads();
    if (tid < RR)
        GA[(size_t)p * RR + tid] = red[0][tid] + red[1][tid] + red[2][tid] + red[3][tid];
}

// ---------------------------------------------------------------------------
// out[t,d] = w0*(Y[2lt,d] + GA[2t]·B2[e0][d,:]) + w1*(Y[2lt+1,d] + GA[2t+1]·B2[e1][d,:])
// Chunked: blockIdx.x = local token lt; t = t0 + lt; Y rows are local pairs.
// ---------------------------------------------------------------------------
__global__ __launch_bounds__(256) void combine_k(const float* __restrict__ Y,
                                                 const float* __restrict__ GA,
                                                 const float* __restrict__ B2,
                                                 const int* __restrict__ pair_e,
                                                 const float* __restrict__ pair_w,
                                                 float* __restrict__ out,
                                                 int t0) {
    const int lt = blockIdx.x;
    const int t = t0 + lt;
    const int tid = threadIdx.x;
    __shared__ float g0[RR], g1[RR];
    if (tid < 16) g0[tid] = GA[(size_t)(2 * t) * RR + tid];
    else if (tid < 32) g1[tid - 16] = GA[(size_t)(2 * t + 1) * RR + (tid - 16)];
    __syncthreads();
    const int e0 = pair_e[2 * t], e1 = pair_e[2 * t + 1];
    const float w0 = pair_w[2 * t], w1 = pair_w[2 * t + 1];
    const float* B2e0 = B2 + (size_t)e0 * DD * RR;
    const float* B2e1 = B2 + (size_t)e1 * DD * RR;
    for (int d = tid; d < DD; d += 256) {
        float l0 = 0.f, l1 = 0.f;
        const float4* b0 = (const float4*)(B2e0 + (size_t)d * RR);
        const float4* b1 = (const float4*)(B2e1 + (size_t)d * RR);
#pragma unroll
        for (int q = 0; q < 4; q++) {
            float4 v0 = b0[q], v1 = b1[q];
            l0 += g0[q * 4 + 0] * v0.x + g0[q * 4 + 1] * v0.y + g0[q * 4 + 2] * v0.z + g0[q * 4 + 3] * v0.w;
            l1 += g1[q * 4 + 0] * v1.x + g1[q * 4 + 1] * v1.y + g1[q * 4 + 2] * v1.z + g1[q * 4 + 3] * v1.w;
        }
        out[(size_t)t * DD + d] = w0 * (Y[(size_t)(2 * lt) * DD + d] + l0)
                                + w1 * (Y[(size_t)(2 * lt + 1) * DD + d] + l1);
    }
}

// ---------------------------------------------------------------------------
extern "C" void kernel_launch(void* const* d_in, const int* in_sizes, int n_in,
                              void* d_out, int out_size, void* d_ws, size_t ws_size,
                              hipStream_t stream) {
    const float* x  = (const float*)d_in[0];
    const float* gw = (const float*)d_in[1];
    const float* W1 = (const float*)d_in[2];
    const float* W3 = (const float*)d_in[3];
    const float* W2 = (const float*)d_in[4];
    const float* A1 = (const float*)d_in[5];
    const float* B1 = (const float*)d_in[6];
    const float* A3 = (const float*)d_in[7];
    const float* B3 = (const float*)d_in[8];
    const float* A2 = (const float*)d_in[9];
    const float* B2 = (const float*)d_in[10];

    float* out    = (float*)d_out;                 // [T*D]
    float* logits = out + (size_t)TT * DD;         // [T*E]

    char* ws = (char*)d_ws;
    size_t off = 0;
    auto carve = [&](size_t bytes) {
        char* p = ws + off;
        off += (bytes + 255) & ~(size_t)255;
        return p;
    };
    // ---- resident buffers (~105 MB) ----
    __bf16* h_bf  = (__bf16*)carve((size_t)TT * DD * 2);        // 33.6 MB
    __bf16* W_all = (__bf16*)carve((size_t)NALL * DD * 2);      // 47.2 MB  rows: W1|W3|A13
    __bf16* W2b   = (__bf16*)carve((size_t)DD * FF * 2);        // 23.1 MB
    float*  GA    = (float*)carve((size_t)NPAIR * RR * 4);      // 1 MB
    int*    pair_e = (int*)carve((size_t)NPAIR * 4);
    float*  pair_w = (float*)carve((size_t)NPAIR * 4);
    size_t fixed_end = off;

    // ---- choose token chunk size C from ws_size (deterministic per call) ----
    // per chunk: base_chunk = C*NALL*2 (Y fp32 aliases it: 2C*DD*4 <= C*NALL*2)
    //            G_chunk    = 2C*FF*2
    int C = TT;   // 8192 -> ~478 MB total
    while (C > 256) {
        size_t need = fixed_end + ((size_t)C * NALL * 2 + 4096) + ((size_t)2 * C * FF * 2 + 4096);
        if (need <= ws_size) break;
        C >>= 1;
    }
    char* base_c_raw = carve((size_t)C * NALL * 2);
    __bf16* base_c = (__bf16*)base_c_raw;
    float*  Y_c    = (float*)base_c_raw;           // aliases base_c (dead by then)
    __bf16* G_c    = (__bf16*)carve((size_t)2 * C * FF * 2);

    // 1. converts (weights + full activation, once)
    cvt_f32_bf16<<<2048, 256, 0, stream>>>(x, h_bf, TT * DD / 4);
    cvt_f32_bf16<<<1024, 256, 0, stream>>>(W1, W_all, FF * DD / 4);
    cvt_f32_bf16<<<1024, 256, 0, stream>>>(W3, W_all + (size_t)FF * DD, FF * DD / 4);
    cvt_f32_bf16<<<1024, 256, 0, stream>>>(W2, W2b, DD * FF / 4);
    cvt_A13<<<512, 256, 0, stream>>>(A1, A3, W_all + (size_t)2 * FF * DD);

    // 2. router (fp32) — writes logits output + pair routing
    router_k<<<TT / 4, 256, 0, stream>>>(x, gw, logits, pair_e, pair_w);

    // 3-6. chunked main pipeline
    for (int t0 = 0; t0 < TT; t0 += C) {
        // base_chunk[C, NALL] = h[t0:t0+C] @ [W1|W3|A13]^T  (bf16 out)
        gemm_bt<1><<<dim3(C / 128, NALL / 128), 256, 0, stream>>>(
            h_bf + (size_t)t0 * DD, W_all, base_c, C, NALL, DD);
        // per-pair SwiGLU + lora1/3 + GA reduction
        g_build<<<2 * C, 256, 0, stream>>>(base_c, B1, B3, A2, pair_e, G_c, GA, 2 * t0);
        // Y[2C, D] = G @ W2^T  (fp32 out, aliases base_c)
        gemm_bt<0><<<dim3(2 * C / 128, DD / 128), 256, 0, stream>>>(
            G_c, W2b, Y_c, 2 * C, DD, FF);
        // combine with routing weights + lora2
        combine_k<<<C, 256, 0, stream>>>(Y_c, GA, B2, pair_e, pair_w, out, t0);
    }
}

// Round 3
// 1907.612 us; speedup vs baseline: 1.3579x; 1.3579x over previous
//
#include <hip/hip_runtime.h>
#include <hip/hip_bf16.h>
#include <stdint.h>

// Problem constants
#define TT   8192      // tokens = B*S
#define DD   2048      // d_model
#define FF   5632      // ffn hidden
#define EE   8         // experts
#define RR   16        // lora rank
#define NALL 11520     // F + F + E*2R = 5632+5632+256
#define NPAIR 16384    // T * TOPK

typedef float  f32x4  __attribute__((ext_vector_type(4)));
typedef __bf16 bf16x8 __attribute__((ext_vector_type(8)));
typedef __bf16 bf16x4 __attribute__((ext_vector_type(4)));

#define AS1CAST(p) ((__attribute__((address_space(1))) void*)(p))
#define AS3CAST(p) ((__attribute__((address_space(3))) void*)(p))

// ---------------------------------------------------------------------------
// f32 -> bf16 convert (float4 vectorized, grid-stride)
// ---------------------------------------------------------------------------
__global__ __launch_bounds__(256) void cvt_f32_bf16(const float* __restrict__ src,
                                                    __bf16* __restrict__ dst, int n4) {
    int stride = gridDim.x * 256;
    for (int i = blockIdx.x * 256 + threadIdx.x; i < n4; i += stride) {
        float4 v = ((const float4*)src)[i];
        bf16x4 o = {(__bf16)v.x, (__bf16)v.y, (__bf16)v.z, (__bf16)v.w};
        ((bf16x4*)dst)[i] = o;
    }
}

// Gather-convert A1/A3 into stacked rows [256][D]: row j=e*32+l, l<16 -> A1[e][l], else A3[e][l-16]
__global__ __launch_bounds__(256) void cvt_A13(const float* __restrict__ A1,
                                               const float* __restrict__ A3,
                                               __bf16* __restrict__ dst) {
    int i = blockIdx.x * 256 + threadIdx.x;   // [0, 256*512)
    int col4 = i & 511;                       // D/4 = 512
    int j = i >> 9;                           // row 0..255
    int e = j >> 5, l = j & 31;
    const float* src = (l < 16) ? (A1 + (size_t)(e * 16 + l) * DD)
                                : (A3 + (size_t)(e * 16 + (l - 16)) * DD);
    float4 v = ((const float4*)src)[col4];
    bf16x4 o = {(__bf16)v.x, (__bf16)v.y, (__bf16)v.z, (__bf16)v.w};
    ((bf16x4*)(dst + (size_t)j * DD))[col4] = o;
}

// A2 [E][R][F] fp32 -> A2t [E][F][R] bf16 (f-major, 16 contiguous bf16 per f)
__global__ __launch_bounds__(256) void cvt_A2t(const float* __restrict__ A2,
                                               __bf16* __restrict__ A2t) {
    int i = blockIdx.x * 256 + threadIdx.x;   // over E*RR*FF = 720896 exactly
    int f = i % FF;
    int r = (i / FF) % RR;
    int e = i / (FF * RR);
    A2t[((size_t)e * FF + f) * RR + r] = (__bf16)A2[i];
}

// ---------------------------------------------------------------------------
// Router: logits (fp32, output #2), top-2 renormalized weights per token
// ---------------------------------------------------------------------------
__global__ __launch_bounds__(256) void router_k(const float* __restrict__ x,
                                                const float* __restrict__ gw,
                                                float* __restrict__ logits,
                                                int* __restrict__ pair_e,
                                                float* __restrict__ pair_w) {
    int t = blockIdx.x * 4 + (threadIdx.x >> 6);
    int lane = threadIdx.x & 63;
    const float* xr = x + (size_t)t * DD;
    float acc[EE];
#pragma unroll
    for (int e = 0; e < EE; e++) acc[e] = 0.f;
    for (int d = lane; d < DD; d += 64) {
        float xv = xr[d];
#pragma unroll
        for (int e = 0; e < EE; e++) acc[e] += xv * gw[e * DD + d];
    }
#pragma unroll
    for (int off = 32; off > 0; off >>= 1) {
#pragma unroll
        for (int e = 0; e < EE; e++) acc[e] += __shfl_down(acc[e], off, 64);
    }
    if (lane == 0) {
        float mx = acc[0];
#pragma unroll
        for (int e = 1; e < EE; e++) mx = fmaxf(mx, acc[e]);
        float p[EE];
#pragma unroll
        for (int e = 0; e < EE; e++) p[e] = __expf(acc[e] - mx);
        int e0 = 0;
#pragma unroll
        for (int e = 1; e < EE; e++) if (p[e] > p[e0]) e0 = e;
        int e1 = (e0 == 0) ? 1 : 0;
#pragma unroll
        for (int e = 0; e < EE; e++) if (e != e0 && p[e] > p[e1]) e1 = e;
        float s = p[e0] + p[e1];
        pair_e[2 * t] = e0;     pair_e[2 * t + 1] = e1;
        pair_w[2 * t] = p[e0] / s; pair_w[2 * t + 1] = p[e1] / s;
#pragma unroll
        for (int e = 0; e < EE; e++) logits[(size_t)t * EE + e] = acc[e];
    }
}

// ---------------------------------------------------------------------------
// m97-style bf16 GEMM, B^T layout: C[M,N] = A[M,K] * B[N,K]^T
// ---------------------------------------------------------------------------
template <int OUT_BF16>
__global__ __launch_bounds__(256) void gemm_bt(const __bf16* __restrict__ A,
                                               const __bf16* __restrict__ B,
                                               void* __restrict__ Cv,
                                               int M, int N, int K) {
    __shared__ __align__(16) __bf16 As[128 * 32];
    __shared__ __align__(16) __bf16 Bs[128 * 32];
    const int tid  = threadIdx.x;
    const int wave = tid >> 6, lane = tid & 63;
    const int quad = lane >> 4, lrow = lane & 15;
    const int m0 = blockIdx.x * 128, n0 = blockIdx.y * 128;

    const int r0  = (tid << 4) >> 6;          // rows 0..63
    const int cb0 = (tid << 4) & 63;
    const size_t ldb = (size_t)K * 2;
    const char* gA0 = (const char*)A + (size_t)(m0 + r0) * ldb + cb0;
    const char* gA1 = (const char*)A + (size_t)(m0 + r0 + 64) * ldb + cb0;
    const char* gB0 = (const char*)B + (size_t)(n0 + r0) * ldb + cb0;
    const char* gB1 = (const char*)B + (size_t)(n0 + r0 + 64) * ldb + cb0;
    char* lA0 = ((char*)As) + (wave << 10);
    char* lA1 = ((char*)As) + 4096 + (wave << 10);
    char* lB0 = ((char*)Bs) + (wave << 10);
    char* lB1 = ((char*)Bs) + 4096 + (wave << 10);

    f32x4 acc[4][4] = {};

    const int abase = ((wave & 1) * 64 + lrow) * 32 + quad * 8;
    const int bbase = ((wave >> 1) * 64 + lrow) * 32 + quad * 8;

    const int KB = K * 2;   // bytes per row
    for (int kb = 0; kb < KB; kb += 64) {
        __syncthreads();
        __builtin_amdgcn_global_load_lds(AS1CAST((void*)(gA0 + kb)), AS3CAST(lA0), 16, 0, 0);
        __builtin_amdgcn_global_load_lds(AS1CAST((void*)(gA1 + kb)), AS3CAST(lA1), 16, 0, 0);
        __builtin_amdgcn_global_load_lds(AS1CAST((void*)(gB0 + kb)), AS3CAST(lB0), 16, 0, 0);
        __builtin_amdgcn_global_load_lds(AS1CAST((void*)(gB1 + kb)), AS3CAST(lB1), 16, 0, 0);
        __syncthreads();

        bf16x8 af[4], bfr[4];
#pragma unroll
        for (int i = 0; i < 4; i++) af[i]  = *(const bf16x8*)&As[abase + i * 16 * 32];
#pragma unroll
        for (int j = 0; j < 4; j++) bfr[j] = *(const bf16x8*)&Bs[bbase + j * 16 * 32];
#pragma unroll
        for (int i = 0; i < 4; i++)
#pragma unroll
            for (int j = 0; j < 4; j++)
                acc[i][j] = __builtin_amdgcn_mfma_f32_16x16x32_bf16(af[i], bfr[j], acc[i][j], 0, 0, 0);
    }

    const int wm = (wave & 1) * 64, wn = (wave >> 1) * 64;
#pragma unroll
    for (int i = 0; i < 4; i++) {
#pragma unroll
        for (int j = 0; j < 4; j++) {
#pragma unroll
            for (int r = 0; r < 4; r++) {
                int row = m0 + wm + i * 16 + quad * 4 + r;
                int col = n0 + wn + j * 16 + lrow;
                float v = acc[i][j][r];
                if (OUT_BF16) ((__bf16*)Cv)[(size_t)row * N + col] = (__bf16)v;
                else          ((float*)Cv)[(size_t)row * N + col] = v;
            }
        }
    }
}

// ---------------------------------------------------------------------------
// g_build2: one PAIR per WAVE, 4 pairs per block. Weights bf16, f-major.
// u1 = base1 + ha1·B1[e][f,:], u3 = base3 + ha3·B3[e][f,:],
// g = silu(u1)*u3 -> G[lp][f]; GA[p][r] = sum_f g*A2t[e][f][r]
// ---------------------------------------------------------------------------
__global__ __launch_bounds__(256) void g_build2(const __bf16* __restrict__ base,
                                                const __bf16* __restrict__ B1b,
                                                const __bf16* __restrict__ B3b,
                                                const __bf16* __restrict__ A2t,
                                                const int* __restrict__ pair_e,
                                                __bf16* __restrict__ G,
                                                float* __restrict__ GA,
                                                int p0) {
    const int wave = threadIdx.x >> 6, lane = threadIdx.x & 63;
    const int lp = blockIdx.x * 4 + wave;
    const int p = p0 + lp;
    const int lt = lp >> 1;
    const int e = pair_e[p];
    const __bf16* brow = base + (size_t)lt * NALL;

    // broadcast-load ha1/ha3 (32 bf16, same address all lanes)
    const bf16x8* hap = (const bf16x8*)(brow + 2 * FF + e * 32);
    bf16x8 h0 = hap[0], h1 = hap[1], h2 = hap[2], h3 = hap[3];
    float ha1[16], ha3[16];
#pragma unroll
    for (int r = 0; r < 8; r++) {
        ha1[r] = (float)h0[r]; ha1[8 + r] = (float)h1[r];
        ha3[r] = (float)h2[r]; ha3[8 + r] = (float)h3[r];
    }
    const __bf16* B1e = B1b + (size_t)e * FF * RR;
    const __bf16* B3e = B3b + (size_t)e * FF * RR;
    const __bf16* A2e = A2t + (size_t)e * FF * RR;
    __bf16* Grow = G + (size_t)lp * FF;

    float ga[16];
#pragma unroll
    for (int r = 0; r < 16; r++) ga[r] = 0.f;

    for (int f = lane; f < FF; f += 64) {
        const bf16x8* b1p = (const bf16x8*)(B1e + (size_t)f * RR);
        const bf16x8* b3p = (const bf16x8*)(B3e + (size_t)f * RR);
        bf16x8 b1l = b1p[0], b1h = b1p[1];
        bf16x8 b3l = b3p[0], b3h = b3p[1];
        float u1 = (float)brow[f];
        float u3 = (float)brow[FF + f];
#pragma unroll
        for (int r = 0; r < 8; r++) {
            u1 += ha1[r] * (float)b1l[r];
            u1 += ha1[8 + r] * (float)b1h[r];
            u3 += ha3[r] * (float)b3l[r];
            u3 += ha3[8 + r] * (float)b3h[r];
        }
        float g = (u1 / (1.f + __expf(-u1))) * u3;
        Grow[f] = (__bf16)g;
        const bf16x8* a2p = (const bf16x8*)(A2e + (size_t)f * RR);
        bf16x8 a2l = a2p[0], a2h = a2p[1];
#pragma unroll
        for (int r = 0; r < 8; r++) {
            ga[r]     += g * (float)a2l[r];
            ga[8 + r] += g * (float)a2h[r];
        }
    }
#pragma unroll
    for (int off = 32; off > 0; off >>= 1) {
#pragma unroll
        for (int r = 0; r < 16; r++) ga[r] += __shfl_down(ga[r], off, 64);
    }
    if (lane == 0) {
#pragma unroll
        for (int r = 0; r < 16; r++) GA[(size_t)p * RR + r] = ga[r];
    }
}

// ---------------------------------------------------------------------------
// out[t,d] = w0*(Y[2lt,d] + GA[2t]·B2[e0][d,:]) + w1*(Y[2lt+1,d] + GA[2t+1]·B2[e1][d,:])
// ---------------------------------------------------------------------------
__global__ __launch_bounds__(256) void combine_k(const float* __restrict__ Y,
                                                 const float* __restrict__ GA,
                                                 const float* __restrict__ B2,
                                                 const int* __restrict__ pair_e,
                                                 const float* __restrict__ pair_w,
                                                 float* __restrict__ out,
                                                 int t0) {
    const int lt = blockIdx.x;
    const int t = t0 + lt;
    const int tid = threadIdx.x;
    __shared__ float g0[RR], g1[RR];
    if (tid < 16) g0[tid] = GA[(size_t)(2 * t) * RR + tid];
    else if (tid < 32) g1[tid - 16] = GA[(size_t)(2 * t + 1) * RR + (tid - 16)];
    __syncthreads();
    const int e0 = pair_e[2 * t], e1 = pair_e[2 * t + 1];
    const float w0 = pair_w[2 * t], w1 = pair_w[2 * t + 1];
    const float* B2e0 = B2 + (size_t)e0 * DD * RR;
    const float* B2e1 = B2 + (size_t)e1 * DD * RR;
    for (int d = tid; d < DD; d += 256) {
        float l0 = 0.f, l1 = 0.f;
        const float4* b0 = (const float4*)(B2e0 + (size_t)d * RR);
        const float4* b1 = (const float4*)(B2e1 + (size_t)d * RR);
#pragma unroll
        for (int q = 0; q < 4; q++) {
            float4 v0 = b0[q], v1 = b1[q];
            l0 += g0[q * 4 + 0] * v0.x + g0[q * 4 + 1] * v0.y + g0[q * 4 + 2] * v0.z + g0[q * 4 + 3] * v0.w;
            l1 += g1[q * 4 + 0] * v1.x + g1[q * 4 + 1] * v1.y + g1[q * 4 + 2] * v1.z + g1[q * 4 + 3] * v1.w;
        }
        out[(size_t)t * DD + d] = w0 * (Y[(size_t)(2 * lt) * DD + d] + l0)
                                + w1 * (Y[(size_t)(2 * lt + 1) * DD + d] + l1);
    }
}

// ---------------------------------------------------------------------------
extern "C" void kernel_launch(void* const* d_in, const int* in_sizes, int n_in,
                              void* d_out, int out_size, void* d_ws, size_t ws_size,
                              hipStream_t stream) {
    const float* x  = (const float*)d_in[0];
    const float* gw = (const float*)d_in[1];
    const float* W1 = (const float*)d_in[2];
    const float* W3 = (const float*)d_in[3];
    const float* W2 = (const float*)d_in[4];
    const float* A1 = (const float*)d_in[5];
    const float* B1 = (const float*)d_in[6];
    const float* A3 = (const float*)d_in[7];
    const float* B3 = (const float*)d_in[8];
    const float* A2 = (const float*)d_in[9];
    const float* B2 = (const float*)d_in[10];

    float* out    = (float*)d_out;                 // [T*D]
    float* logits = out + (size_t)TT * DD;         // [T*E]

    char* ws = (char*)d_ws;
    size_t off = 0;
    auto carve = [&](size_t bytes) {
        char* p = ws + off;
        off += (bytes + 255) & ~(size_t)255;
        return p;
    };
    // ---- resident buffers (~110 MB) ----
    __bf16* h_bf  = (__bf16*)carve((size_t)TT * DD * 2);        // 33.6 MB
    __bf16* W_all = (__bf16*)carve((size_t)NALL * DD * 2);      // 47.2 MB  rows: W1|W3|A13
    __bf16* W2b   = (__bf16*)carve((size_t)DD * FF * 2);        // 23.1 MB
    __bf16* B1b   = (__bf16*)carve((size_t)EE * FF * RR * 2);   // 1.44 MB
    __bf16* B3b   = (__bf16*)carve((size_t)EE * FF * RR * 2);   // 1.44 MB
    __bf16* A2t   = (__bf16*)carve((size_t)EE * FF * RR * 2);   // 1.44 MB
    float*  GA    = (float*)carve((size_t)NPAIR * RR * 4);      // 1 MB
    int*    pair_e = (int*)carve((size_t)NPAIR * 4);
    float*  pair_w = (float*)carve((size_t)NPAIR * 4);
    size_t fixed_end = off;

    // ---- choose token chunk size C from ws_size (deterministic per call) ----
    int C = TT;
    while (C > 256) {
        size_t need = fixed_end + ((size_t)C * NALL * 2 + 4096) + ((size_t)2 * C * FF * 2 + 4096);
        if (need <= ws_size) break;
        C >>= 1;
    }
    char* base_c_raw = carve((size_t)C * NALL * 2);
    __bf16* base_c = (__bf16*)base_c_raw;
    float*  Y_c    = (float*)base_c_raw;           // aliases base_c (dead by then)
    __bf16* G_c    = (__bf16*)carve((size_t)2 * C * FF * 2);

    // 1. converts (weights + full activation, once)
    cvt_f32_bf16<<<2048, 256, 0, stream>>>(x, h_bf, TT * DD / 4);
    cvt_f32_bf16<<<1024, 256, 0, stream>>>(W1, W_all, FF * DD / 4);
    cvt_f32_bf16<<<1024, 256, 0, stream>>>(W3, W_all + (size_t)FF * DD, FF * DD / 4);
    cvt_f32_bf16<<<1024, 256, 0, stream>>>(W2, W2b, DD * FF / 4);
    cvt_A13<<<512, 256, 0, stream>>>(A1, A3, W_all + (size_t)2 * FF * DD);
    cvt_f32_bf16<<<512, 256, 0, stream>>>(B1, B1b, EE * FF * RR / 4);
    cvt_f32_bf16<<<512, 256, 0, stream>>>(B3, B3b, EE * FF * RR / 4);
    cvt_A2t<<<EE * RR * FF / 256, 256, 0, stream>>>(A2, A2t);

    // 2. router (fp32) — writes logits output + pair routing
    router_k<<<TT / 4, 256, 0, stream>>>(x, gw, logits, pair_e, pair_w);

    // 3-6. chunked main pipeline
    for (int t0 = 0; t0 < TT; t0 += C) {
        gemm_bt<1><<<dim3(C / 128, NALL / 128), 256, 0, stream>>>(
            h_bf + (size_t)t0 * DD, W_all, base_c, C, NALL, DD);
        g_build2<<<C / 2, 256, 0, stream>>>(base_c, B1b, B3b, A2t, pair_e, G_c, GA, 2 * t0);
        gemm_bt<0><<<dim3(2 * C / 128, DD / 128), 256, 0, stream>>>(
            G_c, W2b, Y_c, 2 * C, DD, FF);
        combine_k<<<C, 256, 0, stream>>>(Y_c, GA, B2, pair_e, pair_w, out, t0);
    }
}